// Round 5
// baseline (7281.394 us; speedup 1.0000x reference)
//
#include <hip/hip_runtime.h>
#include <hip/hip_cooperative_groups.h>
#include <stdint.h>

namespace cg = cooperative_groups;

// ---------------------------------------------------------------------------
// Discriminator_RNN_Utt: 2-layer GRU (B=1024,T=63,F=257,H=512) + MLP heads.
// v5: ONE persistent cooperative kernel for the whole recurrence.
//   - 512 blocks x 512 threads (2 blocks/CU), grid.sync() per timestep.
//   - Weights bf16, fetched once, L2-resident (no kernel-boundary flush).
//   - L0 fuses the input GEMM (K=288, fp32 x read per phase) + recurrent GEMM.
//   - L1 computes h2 and accumulates the dnn head into x3.
//   - No non-temporal hints (v3 lesson: nt pushed streams to HBM latency).
// ---------------------------------------------------------------------------

typedef __bf16 bf16x8 __attribute__((ext_vector_type(8)));
typedef float f32x4 __attribute__((ext_vector_type(4)));
typedef unsigned int u32x2 __attribute__((ext_vector_type(2)));

__device__ __forceinline__ unsigned short f2bf(float f) {
  unsigned int u = __float_as_uint(f);
  u += 0x7fffu + ((u >> 16) & 1u);   // RNE
  return (unsigned short)(u >> 16);
}
__device__ __forceinline__ float bf2f(unsigned short s) {
  return __uint_as_float(((unsigned int)s) << 16);
}
__device__ __forceinline__ float sigm(float x) { return 1.f / (1.f + __expf(-x)); }
__device__ __forceinline__ float tanh_(float x) { return 1.f - 2.f / (1.f + __expf(2.f * x)); }

__device__ __forceinline__ bf16x8 ld_frag(const unsigned short* p) {
  uint4 u = *(const uint4*)p;
  return __builtin_bit_cast(bf16x8, u);
}
__device__ __forceinline__ void st_bf4(unsigned short* p, const float* f) {
  u32x2 v;
  v[0] = (unsigned)f2bf(f[0]) | ((unsigned)f2bf(f[1]) << 16);
  v[1] = (unsigned)f2bf(f[2]) | ((unsigned)f2bf(f[3]) << 16);
  *(u32x2*)p = v;
}

// ------------------------- fp32 -> bf16 (+row pad) -------------------------
__global__ void conv_pad_kernel(const float* __restrict__ src,
                                unsigned short* __restrict__ dst,
                                int rows, int sk, int dk) {
  int idx = blockIdx.x * 256 + threadIdx.x;  // one per 8 outputs
  int cpr = dk >> 3;
  if (idx >= rows * cpr) return;
  int row = idx / cpr;
  int c0 = (idx - row * cpr) << 3;
  const float* s = src + (size_t)row * sk;
  union { unsigned short v[8]; uint4 u; } t;
#pragma unroll
  for (int j = 0; j < 8; ++j) {
    int c = c0 + j;
    t.v[j] = (c < sk) ? f2bf(s[c]) : (unsigned short)0;
  }
  *(uint4*)(dst + (size_t)row * dk + c0) = t.u;
}

// ---------------- zero a contiguous region (g0,g1,q0,q1,x3) ----------------
__global__ void zero_ws_kernel(uint4* __restrict__ a, int n) {
  int i = blockIdx.x * 256 + threadIdx.x;
  uint4 z = {0u, 0u, 0u, 0u};
  if (i < n) a[i] = z;
}

// --------------------- persistent GRU (whole recurrence) -------------------
// 512 blocks x 512 threads. blocks 0..255: layer0; 256..511: layer1.
// Per block: 128 units (slice = lb&3) x 16 batch rows (lb>>2).
// Phase p: L0 computes h1(t=p) for p<=62; L1 computes h2(t=p-1) for p>=1.
// Ping-pong: at phase p, g[p&1]=h1(p-1), q[p&1]=h2(p-2).
__global__ __launch_bounds__(512, 4) void gru_persist_kernel(
    const float* __restrict__ x,
    const unsigned short* __restrict__ wih0, const float* __restrict__ bih0,
    const unsigned short* __restrict__ whh0, const float* __restrict__ bhh0,
    const unsigned short* __restrict__ wih1, const unsigned short* __restrict__ whh1,
    const float* __restrict__ bih1, const float* __restrict__ bhh1,
    const float* __restrict__ dnnw, float* __restrict__ x3,
    unsigned short* __restrict__ g0, unsigned short* __restrict__ g1,
    unsigned short* __restrict__ q0, unsigned short* __restrict__ q1) {
  cg::grid_group grid = cg::this_grid();
  __shared__ __align__(16) unsigned short sm[16384];  // 32 KB
  const int tid = threadIdx.x;
  const int lane = tid & 63, w = tid >> 6;
  const int lm = lane & 15, lk = lane >> 4;
  const int bid = blockIdx.x;
  const bool isL0 = bid < 256;
  const int lb = isL0 ? bid : bid - 256;
  const int m0 = (lb & 3) * 128;   // unit slice (XCD-friendly: bid%8 fixes lb&3)
  const int b0 = (lb >> 2) * 16;   // 64 batch tiles of 16 rows
  const int urow = m0 + w * 16 + lm;     // A-frag weight row (per gate)
  const int ug = m0 + w * 16 + lk * 4;   // 4 consecutive units per lane

#pragma unroll 1
  for (int p = 0; p < 64; ++p) {
    const unsigned short* gA = (p & 1) ? g1 : g0;
    unsigned short* gB = (p & 1) ? g0 : g1;
    const unsigned short* qA = (p & 1) ? q1 : q0;
    unsigned short* qB = (p & 1) ? q0 : q1;

    if (isL0) {
      if (p <= 62) {
        const int t = p;
        unsigned short* smH = sm;           // h1_prev [16][512] (XOR swizzle)
        unsigned short* smX = sm + 8192;    // x_t bf16 [16][296] (pitch 296)
#pragma unroll
        for (int s = 0; s < 2; ++s) {       // 16 rows x 64 chunks
          int c = tid + (s << 9);
          int row = c >> 6, ch = c & 63, sw = ch ^ (row & 7);
          *(uint4*)&smH[row * 512 + sw * 8] =
              *(const uint4*)(gA + ((size_t)(b0 + row) << 9) + ch * 8);
        }
        for (int c = tid; c < 576; c += 512) {  // 16 rows x 36 chunks
          int row = c / 36, ch = c - row * 36;
          const float* xr = x + ((size_t)(b0 + row) * 63 + t) * 257;
          union { unsigned short v[8]; uint4 u; } tx;
#pragma unroll
          for (int j = 0; j < 8; ++j) {
            int col = ch * 8 + j;
            tx.v[j] = (col < 257) ? f2bf(xr[col]) : (unsigned short)0;
          }
          *(uint4*)&smX[row * 296 + ch * 8] = tx.u;
        }
        __syncthreads();
        f32x4 aR = {0.f, 0.f, 0.f, 0.f}, aZ = {0.f, 0.f, 0.f, 0.f};
        f32x4 aNi = {0.f, 0.f, 0.f, 0.f}, aNh = {0.f, 0.f, 0.f, 0.f};
        for (int kk = 0; kk < 16; ++kk) {   // recurrent K=512
          bf16x8 wr_ = ld_frag(whh0 + ((size_t)urow << 9) + kk * 32 + lk * 8);
          bf16x8 wz_ = ld_frag(whh0 + ((size_t)(512 + urow) << 9) + kk * 32 + lk * 8);
          bf16x8 wn_ = ld_frag(whh0 + ((size_t)(1024 + urow) << 9) + kk * 32 + lk * 8);
          int sw = (kk * 4 + lk) ^ (lm & 7);
          bf16x8 hb = ld_frag(&smH[lm * 512 + sw * 8]);
          aR = __builtin_amdgcn_mfma_f32_16x16x32_bf16(wr_, hb, aR, 0, 0, 0);
          aZ = __builtin_amdgcn_mfma_f32_16x16x32_bf16(wz_, hb, aZ, 0, 0, 0);
          aNh = __builtin_amdgcn_mfma_f32_16x16x32_bf16(wn_, hb, aNh, 0, 0, 0);
        }
        for (int kk = 0; kk < 9; ++kk) {    // input K=288 (padded)
          bf16x8 ir_ = ld_frag(wih0 + (size_t)urow * 288 + kk * 32 + lk * 8);
          bf16x8 iz_ = ld_frag(wih0 + (size_t)(512 + urow) * 288 + kk * 32 + lk * 8);
          bf16x8 in_ = ld_frag(wih0 + (size_t)(1024 + urow) * 288 + kk * 32 + lk * 8);
          bf16x8 xv = ld_frag(&smX[lm * 296 + kk * 32 + lk * 8]);
          aR = __builtin_amdgcn_mfma_f32_16x16x32_bf16(ir_, xv, aR, 0, 0, 0);
          aZ = __builtin_amdgcn_mfma_f32_16x16x32_bf16(iz_, xv, aZ, 0, 0, 0);
          aNi = __builtin_amdgcn_mfma_f32_16x16x32_bf16(in_, xv, aNi, 0, 0, 0);
        }
        const f32x4 bir4 = *(const f32x4*)(bih0 + ug);
        const f32x4 biz4 = *(const f32x4*)(bih0 + 512 + ug);
        const f32x4 bin4 = *(const f32x4*)(bih0 + 1024 + ug);
        const f32x4 bhr4 = *(const f32x4*)(bhh0 + ug);
        const f32x4 bhz4 = *(const f32x4*)(bhh0 + 512 + ug);
        const f32x4 bhn4 = *(const f32x4*)(bhh0 + 1024 + ug);
        int swc = (ug >> 3) ^ (lm & 7);
        const unsigned short* hpp = &smH[lm * 512 + swc * 8 + (ug & 7)];
        float hv[4];
#pragma unroll
        for (int r = 0; r < 4; ++r) {
          float rr = sigm(aR[r] + bir4[r] + bhr4[r]);
          float zz = sigm(aZ[r] + biz4[r] + bhz4[r]);
          float nn = tanh_(aNi[r] + bin4[r] + rr * (aNh[r] + bhn4[r]));
          hv[r] = nn - nn * zz + zz * bf2f(hpp[r]);
        }
        st_bf4(gB + ((size_t)(b0 + lm) << 9) + ug, hv);
      }
    } else {
      if (p >= 1) {
        const int t = p - 1;
        unsigned short* smA = sm;           // h1(t)   [16][512]
        unsigned short* smB = sm + 8192;    // h2(t-1) [16][512]
#pragma unroll
        for (int s = 0; s < 2; ++s) {
          int c = tid + (s << 9);
          int row = c >> 6, ch = c & 63, sw = ch ^ (row & 7);
          size_t go = ((size_t)(b0 + row) << 9) + ch * 8;
          *(uint4*)&smA[row * 512 + sw * 8] = *(const uint4*)(gA + go);
          *(uint4*)&smB[row * 512 + sw * 8] = *(const uint4*)(qA + go);
        }
        __syncthreads();
        f32x4 aI[3], aH[3];
#pragma unroll
        for (int g = 0; g < 3; ++g) {
          aI[g] = {0.f, 0.f, 0.f, 0.f};
          aH[g] = {0.f, 0.f, 0.f, 0.f};
        }
        for (int kk = 0; kk < 16; ++kk) {
          bf16x8 wi[3], wh[3];
#pragma unroll
          for (int g = 0; g < 3; ++g) {
            size_t wro = ((size_t)(g * 512 + urow) << 9) + kk * 32 + lk * 8;
            wi[g] = ld_frag(wih1 + wro);
            wh[g] = ld_frag(whh1 + wro);
          }
          int sw = (kk * 4 + lk) ^ (lm & 7);
          bf16x8 gb = ld_frag(&smA[lm * 512 + sw * 8]);
          bf16x8 qb = ld_frag(&smB[lm * 512 + sw * 8]);
#pragma unroll
          for (int g = 0; g < 3; ++g) {
            aI[g] = __builtin_amdgcn_mfma_f32_16x16x32_bf16(wi[g], gb, aI[g], 0, 0, 0);
            aH[g] = __builtin_amdgcn_mfma_f32_16x16x32_bf16(wh[g], qb, aH[g], 0, 0, 0);
          }
        }
        const f32x4 bir4 = *(const f32x4*)(bih1 + ug);
        const f32x4 biz4 = *(const f32x4*)(bih1 + 512 + ug);
        const f32x4 bin4 = *(const f32x4*)(bih1 + 1024 + ug);
        const f32x4 bhr4 = *(const f32x4*)(bhh1 + ug);
        const f32x4 bhz4 = *(const f32x4*)(bhh1 + 512 + ug);
        const f32x4 bhn4 = *(const f32x4*)(bhh1 + 1024 + ug);
        const f32x4 dw4 = *(const f32x4*)(dnnw + ug);
        int swc = (ug >> 3) ^ (lm & 7);
        const unsigned short* hpp = &smB[lm * 512 + swc * 8 + (ug & 7)];
        float hv[4], v = 0.f;
#pragma unroll
        for (int r = 0; r < 4; ++r) {
          float rr = sigm(aI[0][r] + aH[0][r] + bir4[r] + bhr4[r]);
          float zz = sigm(aI[1][r] + aH[1][r] + biz4[r] + bhz4[r]);
          float nn = tanh_(aI[2][r] + bin4[r] + rr * (aH[2][r] + bhn4[r]));
          hv[r] = nn - nn * zz + zz * bf2f(hpp[r]);
          v += hv[r] * dw4[r];
        }
        st_bf4(qB + ((size_t)(b0 + lm) << 9) + ug, hv);
        // dnn head partial: sum over this wave's 16 units (across lk)
        v += __shfl_xor(v, 16);
        v += __shfl_xor(v, 32);
        __syncthreads();                    // tiles dead; reuse LDS
        float* part = (float*)sm;
        if (tid < 16) part[tid] = 0.f;
        __syncthreads();
        if (lk == 0) atomicAdd(&part[lm], v);
        __syncthreads();
        if (tid < 16) atomicAdd(&x3[(size_t)(b0 + tid) * 63 + t], part[tid]);
      }
    }
    grid.sync();
  }
}

// ------------------------------- heads -------------------------------------
__global__ __launch_bounds__(64) void head_kernel(
    const float* __restrict__ x3, const float* __restrict__ dnn_b,
    const float* __restrict__ w1, const float* __restrict__ b1,
    const float* __restrict__ w2, const float* __restrict__ b2,
    const float* __restrict__ w3, const float* __restrict__ b3,
    float* __restrict__ out) {
  __shared__ float x3s[63], x4[32], x5[16];
  const int b = blockIdx.x, l = threadIdx.x;
  if (l < 63) x3s[l] = x3[(size_t)b * 63 + l] + dnn_b[0];
  __syncthreads();
  if (l < 32) {
    float s = b1[l];
    for (int t = 0; t < 63; ++t) s += x3s[t] * w1[l * 63 + t];
    x4[l] = s;
  }
  __syncthreads();
  if (l < 16) {
    float s = b2[l];
#pragma unroll
    for (int j = 0; j < 32; ++j) s += x4[j] * w2[l * 32 + j];
    x5[l] = s;
  }
  __syncthreads();
  if (l == 0) {
    float s = b3[0];
#pragma unroll
    for (int j = 0; j < 16; ++j) s += x5[j] * w3[j];
    out[b] = s;
  }
}

// ---------------------------------------------------------------------------
extern "C" void kernel_launch(void* const* d_in, const int* in_sizes, int n_in,
                              void* d_out, int out_size, void* d_ws, size_t ws_size,
                              hipStream_t stream) {
  const float* x    = (const float*)d_in[0];
  const float* wih0 = (const float*)d_in[1];
  const float* whh0 = (const float*)d_in[2];
  const float* bih0 = (const float*)d_in[3];
  const float* bhh0 = (const float*)d_in[4];
  const float* wih1 = (const float*)d_in[5];
  const float* whh1 = (const float*)d_in[6];
  const float* bih1 = (const float*)d_in[7];
  const float* bhh1 = (const float*)d_in[8];
  const float* dnnw = (const float*)d_in[9];
  const float* dnnb = (const float*)d_in[10];
  const float* w1   = (const float*)d_in[11];
  const float* b1   = (const float*)d_in[12];
  const float* w2   = (const float*)d_in[13];
  const float* b2   = (const float*)d_in[14];
  const float* w3   = (const float*)d_in[15];
  const float* b3   = (const float*)d_in[16];
  float* out = (float*)d_out;

  char* p = (char*)d_ws;
  auto alloc = [&](size_t bytes) {
    char* r = p;
    p += (bytes + 255) & ~(size_t)255;
    return r;
  };
  // states first (contiguous for one zero pass), then weights; total ~15 MB
  unsigned short* g0 = (unsigned short*)alloc((size_t)1024 * 512 * 2);
  unsigned short* g1 = (unsigned short*)alloc((size_t)1024 * 512 * 2);
  unsigned short* q0 = (unsigned short*)alloc((size_t)1024 * 512 * 2);
  unsigned short* q1 = (unsigned short*)alloc((size_t)1024 * 512 * 2);
  float* x3 = (float*)alloc((size_t)1024 * 63 * 4);
  unsigned short* wih0b = (unsigned short*)alloc((size_t)1536 * 288 * 2);
  unsigned short* whh0b = (unsigned short*)alloc((size_t)1536 * 512 * 2);
  unsigned short* wih1b = (unsigned short*)alloc((size_t)1536 * 512 * 2);
  unsigned short* whh1b = (unsigned short*)alloc((size_t)1536 * 512 * 2);
  (void)ws_size; (void)in_sizes; (void)n_in; (void)out_size;

  // zero g0|g1|q0|q1|x3 (contiguous: 4*1048576 + 258048 = 4452352 B)
  zero_ws_kernel<<<1087, 256, 0, stream>>>((uint4*)g0, 278272);

  // weights -> bf16 (w_ih0 K padded 257->288)
  conv_pad_kernel<<<216, 256, 0, stream>>>(wih0, wih0b, 1536, 257, 288);
  conv_pad_kernel<<<384, 256, 0, stream>>>(whh0, whh0b, 1536, 512, 512);
  conv_pad_kernel<<<384, 256, 0, stream>>>(wih1, wih1b, 1536, 512, 512);
  conv_pad_kernel<<<384, 256, 0, stream>>>(whh1, whh1b, 1536, 512, 512);

  // whole recurrence in one cooperative launch
  void* kargs[] = {
      (void*)&x,
      (void*)&wih0b, (void*)&bih0, (void*)&whh0b, (void*)&bhh0,
      (void*)&wih1b, (void*)&whh1b, (void*)&bih1, (void*)&bhh1,
      (void*)&dnnw, (void*)&x3,
      (void*)&g0, (void*)&g1, (void*)&q0, (void*)&q1,
  };
  hipLaunchCooperativeKernel((void*)gru_persist_kernel, dim3(512), dim3(512),
                             kargs, 0, stream);

  // heads -> out [1024]
  head_kernel<<<1024, 64, 0, stream>>>(x3, dnnb, w1, b1, w2, b2, w3, b3, out);
}

// Round 7
// 3934.632 us; speedup vs baseline: 1.8506x; 1.8506x over previous
//
#include <hip/hip_runtime.h>
#include <stdint.h>

// ---------------------------------------------------------------------------
// Discriminator_RNN_Utt: 2-layer GRU (B=1024,T=63,F=257,H=512) + MLP heads.
// v6: ONE persistent kernel, NO grid.sync. Batch-local producer/consumer sync
// via system-scope atomic flags; h-states written with system-scope atomic
// stores (bypass L2 -> L3, cross-XCD visible); consumers use normal cached
// loads (each address written once, read only after its flag). L2 never
// invalidated -> weights stay L2-resident across all 63 steps.
// 256 blocks x 512 thr: blocks 0..127 = L0, 128..255 = L1.
// Per block: 32-unit slice (lb&15, XCD-aligned via bid%8) x 128 batch rows.
// ---------------------------------------------------------------------------

typedef __bf16 bf16x8 __attribute__((ext_vector_type(8)));
typedef float f32x4 __attribute__((ext_vector_type(4)));
typedef unsigned int u32x2 __attribute__((ext_vector_type(2)));

__device__ __forceinline__ unsigned short f2bf(float f) {
  unsigned int u = __float_as_uint(f);
  u += 0x7fffu + ((u >> 16) & 1u);   // RNE
  return (unsigned short)(u >> 16);
}
__device__ __forceinline__ float bf2f(unsigned short s) {
  return __uint_as_float(((unsigned int)s) << 16);
}
__device__ __forceinline__ unsigned f2bf_pk(float a, float b) {  // RNE pack x2
  unsigned r;
  asm volatile("v_cvt_pk_bf16_f32 %0, %1, %2" : "=v"(r) : "v"(a), "v"(b));
  return r;
}
__device__ __forceinline__ float sigm(float x) { return 1.f / (1.f + __expf(-x)); }
__device__ __forceinline__ float tanh_(float x) { return 1.f - 2.f / (1.f + __expf(2.f * x)); }

__device__ __forceinline__ bf16x8 ld_frag(const unsigned short* p) {
  uint4 u = *(const uint4*)p;
  return __builtin_bit_cast(bf16x8, u);
}

// ------------------------- fp32 -> bf16 (+row pad), weights ----------------
__global__ void conv_pad_kernel(const float* __restrict__ src,
                                unsigned short* __restrict__ dst,
                                int rows, int sk, int dk) {
  int idx = blockIdx.x * 256 + threadIdx.x;
  int cpr = dk >> 3;
  if (idx >= rows * cpr) return;
  int row = idx / cpr;
  int c0 = (idx - row * cpr) << 3;
  const float* s = src + (size_t)row * sk;
  union { unsigned short v[8]; uint4 u; } t;
#pragma unroll
  for (int j = 0; j < 8; ++j) {
    int c = c0 + j;
    t.v[j] = (c < sk) ? f2bf(s[c]) : (unsigned short)0;
  }
  *(uint4*)(dst + (size_t)row * dk + c0) = t.u;
}

// ------------------------- x fp32 [64512][257] -> bf16 [64512][288] --------
__global__ void convx_kernel(const float* __restrict__ src,
                             unsigned short* __restrict__ dst) {
  int idx = blockIdx.x * 256 + threadIdx.x;   // 4 elems per thread
  if (idx >= 64512 * 72) return;
  int row = idx / 72;
  int c0 = (idx - row * 72) << 2;
  const float* s = src + (size_t)row * 257 + c0;
  float f0 = 0.f, f1 = 0.f, f2 = 0.f, f3 = 0.f;
  if (c0 + 4 <= 257) { f0 = s[0]; f1 = s[1]; f2 = s[2]; f3 = s[3]; }
  else {
    if (c0 < 257) f0 = s[0];
    if (c0 + 1 < 257) f1 = s[1];
    if (c0 + 2 < 257) f2 = s[2];
    if (c0 + 3 < 257) f3 = s[3];
  }
  u32x2 o;
  o[0] = f2bf_pk(f0, f1);
  o[1] = f2bf_pk(f2, f3);
  *(u32x2*)(dst + (size_t)row * 288 + c0) = o;
}

// ---------------- zero a contiguous region ---------------------------------
__global__ void zero_ws_kernel(uint4* __restrict__ a, int n) {
  int i = blockIdx.x * 256 + threadIdx.x;
  uint4 z = {0u, 0u, 0u, 0u};
  if (i < n) a[i] = z;
}

// --------------------- persistent GRU --------------------------------------
__device__ __forceinline__ void spin_wait(unsigned int* f, unsigned int tgt) {
  if (threadIdx.x == 0) {
    int guard = 0;
    while (__hip_atomic_load(f, __ATOMIC_RELAXED, __HIP_MEMORY_SCOPE_SYSTEM) < tgt) {
      __builtin_amdgcn_s_sleep(2);
      if (++guard > (1 << 22)) break;   // bailout: wrong answer beats hang
    }
  }
  __syncthreads();   // also orders subsequent loads after the flag observation
}

__device__ __forceinline__ void st_h4_sys(unsigned short* p, const float* hv) {
  unsigned lo = f2bf_pk(hv[0], hv[1]);
  unsigned hi = f2bf_pk(hv[2], hv[3]);
  unsigned long long v = ((unsigned long long)hi << 32) | lo;
  __hip_atomic_store((unsigned long long*)p, v, __ATOMIC_RELAXED,
                     __HIP_MEMORY_SCOPE_SYSTEM);
}

__global__ __launch_bounds__(512) void gru_persist_kernel(
    const unsigned short* __restrict__ xb,     // [64512][288] bf16
    const unsigned short* __restrict__ wih0, const float* __restrict__ bih0,
    const unsigned short* __restrict__ whh0, const float* __restrict__ bhh0,
    const unsigned short* __restrict__ wih1, const unsigned short* __restrict__ whh1,
    const float* __restrict__ bih1, const float* __restrict__ bhh1,
    const float* __restrict__ dnnw, float* __restrict__ x3,
    unsigned short* __restrict__ S1,           // [64][1024][512] bf16
    unsigned short* __restrict__ S2,           // [64][1024][512] bf16
    unsigned int* __restrict__ flags) {        // fL0[64][8], fL1[64][8]
  const int tid = threadIdx.x;
  const int lane = tid & 63;
  const int wv = tid >> 6;                 // 8 waves = 8 batch n-groups
  const int lm = lane & 15, lk = lane >> 4;
  const int bid = blockIdx.x;
  const bool isL0 = bid < 128;
  const int lb = isL0 ? bid : bid - 128;
  const int slice = lb & 15, bt = lb >> 4; // slice: bid%8 -> XCD-aligned
  const int u0 = slice * 32;
  const int brow = bt * 128 + wv * 16 + lm;
  const size_t browK = (size_t)brow << 9;
  unsigned int* fL0 = flags;
  unsigned int* fL1 = flags + 512;

  if (isL0) {
#pragma unroll 1
    for (int t = 0; t < 63; ++t) {
      if (t > 0) spin_wait(&fL0[t * 8 + bt], 16);
      const unsigned short* S1t = S1 + ((size_t)t << 19);
      unsigned short* S1n = S1 + ((size_t)(t + 1) << 19);
      f32x4 aR[2], aZ[2], aNh[2], aNi[2];
#pragma unroll
      for (int mf = 0; mf < 2; ++mf) {
        aR[mf] = {0.f, 0.f, 0.f, 0.f}; aZ[mf] = {0.f, 0.f, 0.f, 0.f};
        aNh[mf] = {0.f, 0.f, 0.f, 0.f}; aNi[mf] = {0.f, 0.f, 0.f, 0.f};
      }
#pragma unroll 4
      for (int kk = 0; kk < 16; ++kk) {    // recurrent K=512 (h from L3/L2)
        bf16x8 hb = ld_frag(S1t + browK + kk * 32 + lk * 8);
#pragma unroll
        for (int mf = 0; mf < 2; ++mf) {
          const unsigned short* wp =
              whh0 + ((size_t)(u0 + mf * 16 + lm) << 9) + kk * 32 + lk * 8;
          aR[mf] = __builtin_amdgcn_mfma_f32_16x16x32_bf16(ld_frag(wp), hb, aR[mf], 0, 0, 0);
          aZ[mf] = __builtin_amdgcn_mfma_f32_16x16x32_bf16(ld_frag(wp + (512 << 9)), hb, aZ[mf], 0, 0, 0);
          aNh[mf] = __builtin_amdgcn_mfma_f32_16x16x32_bf16(ld_frag(wp + (1024 << 9)), hb, aNh[mf], 0, 0, 0);
        }
      }
      const unsigned short* xr = xb + ((size_t)brow * 63 + t) * 288;
#pragma unroll 3
      for (int kk = 0; kk < 9; ++kk) {     // input K=288 (bf16, padded)
        bf16x8 xv = ld_frag(xr + kk * 32 + lk * 8);
#pragma unroll
        for (int mf = 0; mf < 2; ++mf) {
          const unsigned short* wp =
              wih0 + (size_t)(u0 + mf * 16 + lm) * 288 + kk * 32 + lk * 8;
          aR[mf] = __builtin_amdgcn_mfma_f32_16x16x32_bf16(ld_frag(wp), xv, aR[mf], 0, 0, 0);
          aZ[mf] = __builtin_amdgcn_mfma_f32_16x16x32_bf16(ld_frag(wp + 512 * 288), xv, aZ[mf], 0, 0, 0);
          aNi[mf] = __builtin_amdgcn_mfma_f32_16x16x32_bf16(ld_frag(wp + 1024 * 288), xv, aNi[mf], 0, 0, 0);
        }
      }
#pragma unroll
      for (int mf = 0; mf < 2; ++mf) {
        const int ug = u0 + mf * 16 + lk * 4;
        const f32x4 bir = *(const f32x4*)(bih0 + ug);
        const f32x4 biz = *(const f32x4*)(bih0 + 512 + ug);
        const f32x4 bin = *(const f32x4*)(bih0 + 1024 + ug);
        const f32x4 bhr = *(const f32x4*)(bhh0 + ug);
        const f32x4 bhz = *(const f32x4*)(bhh0 + 512 + ug);
        const f32x4 bhn = *(const f32x4*)(bhh0 + 1024 + ug);
        u32x2 hpu = *(const u32x2*)(S1t + browK + ug);
        float hv[4];
#pragma unroll
        for (int r = 0; r < 4; ++r) {
          float hp = bf2f((unsigned short)((hpu[r >> 1] >> ((r & 1) * 16)) & 0xffff));
          float rr = sigm(aR[mf][r] + bir[r] + bhr[r]);
          float zz = sigm(aZ[mf][r] + biz[r] + bhz[r]);
          float nn = tanh_(aNi[mf][r] + bin[r] + rr * (aNh[mf][r] + bhn[r]));
          hv[r] = nn - nn * zz + zz * hp;
        }
        st_h4_sys(S1n + browK + ug, hv);
      }
      __syncthreads();   // drains every wave's stores (vmcnt0 before barrier)
      if (tid == 0)
        __hip_atomic_fetch_add(&fL0[(t + 1) * 8 + bt], 1u, __ATOMIC_RELAXED,
                               __HIP_MEMORY_SCOPE_SYSTEM);
    }
  } else {
#pragma unroll 1
    for (int t = 0; t < 63; ++t) {
      spin_wait(&fL0[(t + 1) * 8 + bt], 16);           // h1(t) ready
      if (t > 0) spin_wait(&fL1[t * 8 + bt], 16);      // h2(t-1) ready
      const unsigned short* S1c = S1 + ((size_t)(t + 1) << 19);
      const unsigned short* S2t = S2 + ((size_t)t << 19);
      unsigned short* S2n = S2 + ((size_t)(t + 1) << 19);
      f32x4 aIr[2], aIz[2], aIn[2], aHr[2], aHz[2], aHn[2];
#pragma unroll
      for (int mf = 0; mf < 2; ++mf) {
        aIr[mf] = {0.f, 0.f, 0.f, 0.f}; aIz[mf] = {0.f, 0.f, 0.f, 0.f};
        aIn[mf] = {0.f, 0.f, 0.f, 0.f}; aHr[mf] = {0.f, 0.f, 0.f, 0.f};
        aHz[mf] = {0.f, 0.f, 0.f, 0.f}; aHn[mf] = {0.f, 0.f, 0.f, 0.f};
      }
#pragma unroll 2
      for (int kk = 0; kk < 16; ++kk) {
        bf16x8 gb = ld_frag(S1c + browK + kk * 32 + lk * 8);
        bf16x8 qb = ld_frag(S2t + browK + kk * 32 + lk * 8);
#pragma unroll
        for (int mf = 0; mf < 2; ++mf) {
          const size_t wro = ((size_t)(u0 + mf * 16 + lm) << 9) + kk * 32 + lk * 8;
          aIr[mf] = __builtin_amdgcn_mfma_f32_16x16x32_bf16(ld_frag(wih1 + wro), gb, aIr[mf], 0, 0, 0);
          aIz[mf] = __builtin_amdgcn_mfma_f32_16x16x32_bf16(ld_frag(wih1 + wro + ((size_t)512 << 9)), gb, aIz[mf], 0, 0, 0);
          aIn[mf] = __builtin_amdgcn_mfma_f32_16x16x32_bf16(ld_frag(wih1 + wro + ((size_t)1024 << 9)), gb, aIn[mf], 0, 0, 0);
          aHr[mf] = __builtin_amdgcn_mfma_f32_16x16x32_bf16(ld_frag(whh1 + wro), qb, aHr[mf], 0, 0, 0);
          aHz[mf] = __builtin_amdgcn_mfma_f32_16x16x32_bf16(ld_frag(whh1 + wro + ((size_t)512 << 9)), qb, aHz[mf], 0, 0, 0);
          aHn[mf] = __builtin_amdgcn_mfma_f32_16x16x32_bf16(ld_frag(whh1 + wro + ((size_t)1024 << 9)), qb, aHn[mf], 0, 0, 0);
        }
      }
      float v = 0.f;
#pragma unroll
      for (int mf = 0; mf < 2; ++mf) {
        const int ug = u0 + mf * 16 + lk * 4;
        const f32x4 bir = *(const f32x4*)(bih1 + ug);
        const f32x4 biz = *(const f32x4*)(bih1 + 512 + ug);
        const f32x4 bin = *(const f32x4*)(bih1 + 1024 + ug);
        const f32x4 bhr = *(const f32x4*)(bhh1 + ug);
        const f32x4 bhz = *(const f32x4*)(bhh1 + 512 + ug);
        const f32x4 bhn = *(const f32x4*)(bhh1 + 1024 + ug);
        const f32x4 dw4 = *(const f32x4*)(dnnw + ug);
        u32x2 hpu = *(const u32x2*)(S2t + browK + ug);
        float hv[4];
#pragma unroll
        for (int r = 0; r < 4; ++r) {
          float hp = bf2f((unsigned short)((hpu[r >> 1] >> ((r & 1) * 16)) & 0xffff));
          float rr = sigm(aIr[mf][r] + bir[r] + aHr[mf][r] + bhr[r]);
          float zz = sigm(aIz[mf][r] + biz[r] + aHz[mf][r] + bhz[r]);
          float nn = tanh_(aIn[mf][r] + bin[r] + rr * (aHn[mf][r] + bhn[r]));
          hv[r] = nn - nn * zz + zz * hp;
          v += hv[r] * dw4[r];
        }
        st_h4_sys(S2n + browK + ug, hv);
      }
      // dnn head: v currently = partial over this lane's 8 units (2 mf x 4).
      v += __shfl_xor(v, 16);
      v += __shfl_xor(v, 32);          // sum over lk -> all 32 block units
      if (lk == 0) atomicAdd(&x3[(size_t)brow * 63 + t], v);
      __syncthreads();
      if (tid == 0)
        __hip_atomic_fetch_add(&fL1[(t + 1) * 8 + bt], 1u, __ATOMIC_RELAXED,
                               __HIP_MEMORY_SCOPE_SYSTEM);
    }
  }
}

// ------------------------------- heads -------------------------------------
__global__ __launch_bounds__(64) void head_kernel(
    const float* __restrict__ x3, const float* __restrict__ dnn_b,
    const float* __restrict__ w1, const float* __restrict__ b1,
    const float* __restrict__ w2, const float* __restrict__ b2,
    const float* __restrict__ w3, const float* __restrict__ b3,
    float* __restrict__ out) {
  __shared__ float x3s[63], x4[32], x5[16];
  const int b = blockIdx.x, l = threadIdx.x;
  if (l < 63) x3s[l] = x3[(size_t)b * 63 + l] + dnn_b[0];
  __syncthreads();
  if (l < 32) {
    float s = b1[l];
    for (int t = 0; t < 63; ++t) s += x3s[t] * w1[l * 63 + t];
    x4[l] = s;
  }
  __syncthreads();
  if (l < 16) {
    float s = b2[l];
#pragma unroll
    for (int j = 0; j < 32; ++j) s += x4[j] * w2[l * 32 + j];
    x5[l] = s;
  }
  __syncthreads();
  if (l == 0) {
    float s = b3[0];
#pragma unroll
    for (int j = 0; j < 16; ++j) s += x5[j] * w3[j];
    out[b] = s;
  }
}

// ---------------------------------------------------------------------------
extern "C" void kernel_launch(void* const* d_in, const int* in_sizes, int n_in,
                              void* d_out, int out_size, void* d_ws, size_t ws_size,
                              hipStream_t stream) {
  const float* x    = (const float*)d_in[0];
  const float* wih0 = (const float*)d_in[1];
  const float* whh0 = (const float*)d_in[2];
  const float* bih0 = (const float*)d_in[3];
  const float* bhh0 = (const float*)d_in[4];
  const float* wih1 = (const float*)d_in[5];
  const float* whh1 = (const float*)d_in[6];
  const float* bih1 = (const float*)d_in[7];
  const float* bhh1 = (const float*)d_in[8];
  const float* dnnw = (const float*)d_in[9];
  const float* dnnb = (const float*)d_in[10];
  const float* w1   = (const float*)d_in[11];
  const float* b1   = (const float*)d_in[12];
  const float* w2   = (const float*)d_in[13];
  const float* b2   = (const float*)d_in[14];
  const float* w3   = (const float*)d_in[15];
  const float* b3   = (const float*)d_in[16];
  float* out = (float*)d_out;

  char* p = (char*)d_ws;
  auto alloc = [&](size_t bytes) {
    char* r = p;
    p += (bytes + 255) & ~(size_t)255;
    return r;
  };
  // total ~176 MB
  unsigned short* xbuf = (unsigned short*)alloc((size_t)64512 * 288 * 2);
  unsigned short* S1   = (unsigned short*)alloc((size_t)64 * 1024 * 512 * 2);
  unsigned short* S2   = (unsigned short*)alloc((size_t)64 * 1024 * 512 * 2);
  float* x3            = (float*)alloc((size_t)1024 * 63 * 4);      // 258048
  unsigned int* flags  = (unsigned int*)alloc(4096);                // contiguous w/ x3
  unsigned short* wih0b = (unsigned short*)alloc((size_t)1536 * 288 * 2);
  unsigned short* whh0b = (unsigned short*)alloc((size_t)1536 * 512 * 2);
  unsigned short* wih1b = (unsigned short*)alloc((size_t)1536 * 512 * 2);
  unsigned short* whh1b = (unsigned short*)alloc((size_t)1536 * 512 * 2);
  (void)ws_size; (void)in_sizes; (void)n_in; (void)out_size;

  // zero: S1 slot0, S2 slot0, x3+flags
  zero_ws_kernel<<<256, 256, 0, stream>>>((uint4*)S1, 65536);
  zero_ws_kernel<<<256, 256, 0, stream>>>((uint4*)S2, 65536);
  zero_ws_kernel<<<65, 256, 0, stream>>>((uint4*)x3, 16416);

  // x -> bf16 padded [64512][288]; weights -> bf16
  convx_kernel<<<18144, 256, 0, stream>>>(x, xbuf);
  conv_pad_kernel<<<216, 256, 0, stream>>>(wih0, wih0b, 1536, 257, 288);
  conv_pad_kernel<<<384, 256, 0, stream>>>(whh0, whh0b, 1536, 512, 512);
  conv_pad_kernel<<<384, 256, 0, stream>>>(wih1, wih1b, 1536, 512, 512);
  conv_pad_kernel<<<384, 256, 0, stream>>>(whh1, whh1b, 1536, 512, 512);

  // whole recurrence: one persistent kernel, flag-synced, no grid.sync
  gru_persist_kernel<<<256, 512, 0, stream>>>(
      xbuf, wih0b, bih0, whh0b, bhh0, wih1b, whh1b, bih1, bhh1,
      dnnw, x3, S1, S2, flags);

  // heads -> out [1024]
  head_kernel<<<1024, 64, 0, stream>>>(x3, dnnb, w1, b1, w2, b2, w3, b3, out);
}

// Round 9
// 1273.037 us; speedup vs baseline: 5.7197x; 3.0907x over previous
//
#include <hip/hip_runtime.h>
#include <stdint.h>

// ---------------------------------------------------------------------------
// Discriminator_RNN_Utt: 2-layer GRU (B=1024,T=63,F=257,H=512) + MLP heads.
// v7: persistent flag-synced kernel (v6 protocol) + WEIGHTS IN LDS
// (fragment-ordered, loaded once, reused 63 steps -> zero steady-state weight
// fetch) + batch-tile-per-XCD grid mapping (bt = bid%8).
// 256 blocks x 512 thr, 1 block/CU, 160 KB dynamic LDS.
//   bid -> bt = bid%8 (batch tile, 128 rows), j = bid/8: j<16 L0 slice j,
//   j>=16 L1 slice j-16. Slice = 32 units.
// ---------------------------------------------------------------------------

typedef __bf16 bf16x8 __attribute__((ext_vector_type(8)));
typedef float f32x4 __attribute__((ext_vector_type(4)));
typedef unsigned int u32x2 __attribute__((ext_vector_type(2)));

__device__ __forceinline__ unsigned short f2bf(float f) {
  unsigned int u = __float_as_uint(f);
  u += 0x7fffu + ((u >> 16) & 1u);   // RNE
  return (unsigned short)(u >> 16);
}
__device__ __forceinline__ float bf2f(unsigned short s) {
  return __uint_as_float(((unsigned int)s) << 16);
}
__device__ __forceinline__ unsigned f2bf_pk(float a, float b) {  // RNE pack x2
  unsigned r;
  asm volatile("v_cvt_pk_bf16_f32 %0, %1, %2" : "=v"(r) : "v"(a), "v"(b));
  return r;
}
__device__ __forceinline__ float sigm(float x) { return 1.f / (1.f + __expf(-x)); }
__device__ __forceinline__ float tanh_(float x) { return 1.f - 2.f / (1.f + __expf(2.f * x)); }

__device__ __forceinline__ bf16x8 ld_frag(const unsigned short* p) {
  uint4 u = *(const uint4*)p;
  return __builtin_bit_cast(bf16x8, u);
}

// ------------------------- fp32 -> bf16 (+row pad), weights ----------------
__global__ void conv_pad_kernel(const float* __restrict__ src,
                                unsigned short* __restrict__ dst,
                                int rows, int sk, int dk) {
  int idx = blockIdx.x * 256 + threadIdx.x;
  int cpr = dk >> 3;
  if (idx >= rows * cpr) return;
  int row = idx / cpr;
  int c0 = (idx - row * cpr) << 3;
  const float* s = src + (size_t)row * sk;
  union { unsigned short v[8]; uint4 u; } t;
#pragma unroll
  for (int j = 0; j < 8; ++j) {
    int c = c0 + j;
    t.v[j] = (c < sk) ? f2bf(s[c]) : (unsigned short)0;
  }
  *(uint4*)(dst + (size_t)row * dk + c0) = t.u;
}

// ------------------------- x fp32 [64512][257] -> bf16 [64512][288] --------
__global__ void convx_kernel(const float* __restrict__ src,
                             unsigned short* __restrict__ dst) {
  int idx = blockIdx.x * 256 + threadIdx.x;   // 4 elems per thread
  if (idx >= 64512 * 72) return;
  int row = idx / 72;
  int c0 = (idx - row * 72) << 2;
  const float* s = src + (size_t)row * 257 + c0;
  float f0 = 0.f, f1 = 0.f, f2 = 0.f, f3 = 0.f;
  if (c0 + 4 <= 257) { f0 = s[0]; f1 = s[1]; f2 = s[2]; f3 = s[3]; }
  else {
    if (c0 < 257) f0 = s[0];
    if (c0 + 1 < 257) f1 = s[1];
    if (c0 + 2 < 257) f2 = s[2];
    if (c0 + 3 < 257) f3 = s[3];
  }
  u32x2 o;
  o[0] = f2bf_pk(f0, f1);
  o[1] = f2bf_pk(f2, f3);
  *(u32x2*)(dst + (size_t)row * 288 + c0) = o;
}

// ---------------- zero a contiguous region ---------------------------------
__global__ void zero_ws_kernel(uint4* __restrict__ a, int n) {
  int i = blockIdx.x * 256 + threadIdx.x;
  uint4 z = {0u, 0u, 0u, 0u};
  if (i < n) a[i] = z;
}

// --------------------- persistent GRU --------------------------------------
__device__ __forceinline__ void spin_wait(unsigned int* f, unsigned int tgt) {
  if (threadIdx.x == 0) {
    int guard = 0;
    while (__hip_atomic_load(f, __ATOMIC_RELAXED, __HIP_MEMORY_SCOPE_SYSTEM) < tgt) {
      __builtin_amdgcn_s_sleep(2);
      if (++guard > (1 << 22)) break;   // bailout: wrong answer beats hang
    }
  }
  __syncthreads();   // orders subsequent loads after the flag observation
}

__device__ __forceinline__ void st_h4_sys(unsigned short* p, const float* hv) {
  unsigned lo = f2bf_pk(hv[0], hv[1]);
  unsigned hi = f2bf_pk(hv[2], hv[3]);
  unsigned long long v = ((unsigned long long)hi << 32) | lo;
  __hip_atomic_store((unsigned long long*)p, v, __ATOMIC_RELAXED,
                     __HIP_MEMORY_SCOPE_SYSTEM);
}

// LDS weight layout (bf16 units), per block:
//  L0: [0, 49152)  whh0 slice, frag f = (kk*2+mf)*3+g   -> smw[f*512 + lane*8]
//      [49152, 76800) wih0 slice, same frag formula (kk<9)
//  L1: [0, 49152)  whh1 slice, frag f = (kk*2+mf)*3+g
//      [49152, 81920) wih1 slice gates r,z: f = (kk*2+mf)*2+g
__global__ __launch_bounds__(512) void gru_persist_kernel(
    const unsigned short* __restrict__ xb,     // [64512][288] bf16
    const unsigned short* __restrict__ wih0, const float* __restrict__ bih0,
    const unsigned short* __restrict__ whh0, const float* __restrict__ bhh0,
    const unsigned short* __restrict__ wih1, const unsigned short* __restrict__ whh1,
    const float* __restrict__ bih1, const float* __restrict__ bhh1,
    const float* __restrict__ dnnw, float* __restrict__ x3,
    unsigned short* __restrict__ S1,           // [64][1024][512] bf16
    unsigned short* __restrict__ S2,           // [64][1024][512] bf16
    unsigned int* __restrict__ flags) {        // fL0[64][8], fL1[64][8]
  extern __shared__ unsigned short smw[];
  const int tid = threadIdx.x;
  const int lane = tid & 63;
  const int wv = tid >> 6;                 // 8 waves = 8 batch n-groups
  const int lm = lane & 15, lk = lane >> 4;
  const int bid = blockIdx.x;
  const int bt = bid & 7;                  // batch tile -> XCD (round-robin)
  const int j = bid >> 3;
  const bool isL0 = j < 16;
  const int slice = isL0 ? j : j - 16;
  const int u0 = slice * 32;
  const int brow = bt * 128 + wv * 16 + lm;
  const size_t browK = (size_t)brow << 9;
  unsigned int* fL0 = flags;
  unsigned int* fL1 = flags + 512;

  // ---- prologue: stage this block's weight slice into LDS (frag order) ----
  if (isL0) {
    for (int i = tid; i < 6144; i += 512) {          // whh0: 96 KB
      int ln = i & 63, r2 = i >> 6;
      int g = r2 % 3, r3 = r2 / 3;
      int mf = r3 & 1, kk = r3 >> 1;
      *(uint4*)&smw[i * 8] = *(const uint4*)(
          whh0 + (size_t)(g * 512 + u0 + mf * 16 + (ln & 15)) * 512 + kk * 32 + (ln >> 4) * 8);
    }
    for (int i = tid; i < 3456; i += 512) {          // wih0: 54 KB
      int ln = i & 63, r2 = i >> 6;
      int g = r2 % 3, r3 = r2 / 3;
      int mf = r3 & 1, kk = r3 >> 1;
      *(uint4*)&smw[49152 + i * 8] = *(const uint4*)(
          wih0 + (size_t)(g * 512 + u0 + mf * 16 + (ln & 15)) * 288 + kk * 32 + (ln >> 4) * 8);
    }
  } else {
    for (int i = tid; i < 6144; i += 512) {          // whh1: 96 KB
      int ln = i & 63, r2 = i >> 6;
      int g = r2 % 3, r3 = r2 / 3;
      int mf = r3 & 1, kk = r3 >> 1;
      *(uint4*)&smw[i * 8] = *(const uint4*)(
          whh1 + (size_t)(g * 512 + u0 + mf * 16 + (ln & 15)) * 512 + kk * 32 + (ln >> 4) * 8);
    }
    for (int i = tid; i < 4096; i += 512) {          // wih1 gates r,z: 64 KB
      int ln = i & 63, r2 = i >> 6;
      int g = r2 & 1, r4 = r2 >> 1;
      int mf = r4 & 1, kk = r4 >> 1;
      *(uint4*)&smw[49152 + i * 8] = *(const uint4*)(
          wih1 + (size_t)(g * 512 + u0 + mf * 16 + (ln & 15)) * 512 + kk * 32 + (ln >> 4) * 8);
    }
  }
  __syncthreads();

  if (isL0) {
#pragma unroll 1
    for (int t = 0; t < 63; ++t) {
      if (t > 0) spin_wait(&fL0[t * 8 + bt], 16);
      const unsigned short* S1t = S1 + ((size_t)t << 19);
      unsigned short* S1n = S1 + ((size_t)(t + 1) << 19);
      f32x4 aR[2], aZ[2], aNh[2], aNi[2];
#pragma unroll
      for (int mf = 0; mf < 2; ++mf) {
        aR[mf] = {0.f, 0.f, 0.f, 0.f}; aZ[mf] = {0.f, 0.f, 0.f, 0.f};
        aNh[mf] = {0.f, 0.f, 0.f, 0.f}; aNi[mf] = {0.f, 0.f, 0.f, 0.f};
      }
#pragma unroll 4
      for (int kk = 0; kk < 16; ++kk) {    // recurrent K=512, weights from LDS
        bf16x8 hb = ld_frag(S1t + browK + kk * 32 + lk * 8);
#pragma unroll
        for (int mf = 0; mf < 2; ++mf) {
          const int f = ((kk * 2 + mf) * 3) * 512 + lane * 8;
          aR[mf]  = __builtin_amdgcn_mfma_f32_16x16x32_bf16(ld_frag(&smw[f]), hb, aR[mf], 0, 0, 0);
          aZ[mf]  = __builtin_amdgcn_mfma_f32_16x16x32_bf16(ld_frag(&smw[f + 512]), hb, aZ[mf], 0, 0, 0);
          aNh[mf] = __builtin_amdgcn_mfma_f32_16x16x32_bf16(ld_frag(&smw[f + 1024]), hb, aNh[mf], 0, 0, 0);
        }
      }
      const unsigned short* xr = xb + ((size_t)brow * 63 + t) * 288;
#pragma unroll 3
      for (int kk = 0; kk < 9; ++kk) {     // input K=288, weights from LDS
        bf16x8 xv = ld_frag(xr + kk * 32 + lk * 8);
#pragma unroll
        for (int mf = 0; mf < 2; ++mf) {
          const int f = 49152 + ((kk * 2 + mf) * 3) * 512 + lane * 8;
          aR[mf]  = __builtin_amdgcn_mfma_f32_16x16x32_bf16(ld_frag(&smw[f]), xv, aR[mf], 0, 0, 0);
          aZ[mf]  = __builtin_amdgcn_mfma_f32_16x16x32_bf16(ld_frag(&smw[f + 512]), xv, aZ[mf], 0, 0, 0);
          aNi[mf] = __builtin_amdgcn_mfma_f32_16x16x32_bf16(ld_frag(&smw[f + 1024]), xv, aNi[mf], 0, 0, 0);
        }
      }
#pragma unroll
      for (int mf = 0; mf < 2; ++mf) {
        const int ug = u0 + mf * 16 + lk * 4;
        const f32x4 bir = *(const f32x4*)(bih0 + ug);
        const f32x4 biz = *(const f32x4*)(bih0 + 512 + ug);
        const f32x4 bin = *(const f32x4*)(bih0 + 1024 + ug);
        const f32x4 bhr = *(const f32x4*)(bhh0 + ug);
        const f32x4 bhz = *(const f32x4*)(bhh0 + 512 + ug);
        const f32x4 bhn = *(const f32x4*)(bhh0 + 1024 + ug);
        u32x2 hpu = *(const u32x2*)(S1t + browK + ug);
        float hv[4];
#pragma unroll
        for (int r = 0; r < 4; ++r) {
          float hp = bf2f((unsigned short)((hpu[r >> 1] >> ((r & 1) * 16)) & 0xffff));
          float rr = sigm(aR[mf][r] + bir[r] + bhr[r]);
          float zz = sigm(aZ[mf][r] + biz[r] + bhz[r]);
          float nn = tanh_(aNi[mf][r] + bin[r] + rr * (aNh[mf][r] + bhn[r]));
          hv[r] = nn - nn * zz + zz * hp;
        }
        st_h4_sys(S1n + browK + ug, hv);
      }
      __syncthreads();   // drains every wave's stores before flag
      if (tid == 0)
        __hip_atomic_fetch_add(&fL0[(t + 1) * 8 + bt], 1u, __ATOMIC_RELAXED,
                               __HIP_MEMORY_SCOPE_SYSTEM);
    }
  } else {
#pragma unroll 1
    for (int t = 0; t < 63; ++t) {
      spin_wait(&fL0[(t + 1) * 8 + bt], 16);           // h1(t) ready
      if (t > 0) spin_wait(&fL1[t * 8 + bt], 16);      // h2(t-1) ready
      const unsigned short* S1c = S1 + ((size_t)(t + 1) << 19);
      const unsigned short* S2t = S2 + ((size_t)t << 19);
      unsigned short* S2n = S2 + ((size_t)(t + 1) << 19);
      f32x4 aIr[2], aIz[2], aIn[2], aHr[2], aHz[2], aHn[2];
#pragma unroll
      for (int mf = 0; mf < 2; ++mf) {
        aIr[mf] = {0.f, 0.f, 0.f, 0.f}; aIz[mf] = {0.f, 0.f, 0.f, 0.f};
        aIn[mf] = {0.f, 0.f, 0.f, 0.f}; aHr[mf] = {0.f, 0.f, 0.f, 0.f};
        aHz[mf] = {0.f, 0.f, 0.f, 0.f}; aHn[mf] = {0.f, 0.f, 0.f, 0.f};
      }
#pragma unroll 2
      for (int kk = 0; kk < 16; ++kk) {
        bf16x8 gb = ld_frag(S1c + browK + kk * 32 + lk * 8);
        bf16x8 qb = ld_frag(S2t + browK + kk * 32 + lk * 8);
#pragma unroll
        for (int mf = 0; mf < 2; ++mf) {
          const int f3 = ((kk * 2 + mf) * 3) * 512 + lane * 8;          // whh1 LDS
          const int f2 = 49152 + ((kk * 2 + mf) * 2) * 512 + lane * 8;  // wih1 r,z LDS
          aIr[mf] = __builtin_amdgcn_mfma_f32_16x16x32_bf16(ld_frag(&smw[f2]), gb, aIr[mf], 0, 0, 0);
          aIz[mf] = __builtin_amdgcn_mfma_f32_16x16x32_bf16(ld_frag(&smw[f2 + 512]), gb, aIz[mf], 0, 0, 0);
          aIn[mf] = __builtin_amdgcn_mfma_f32_16x16x32_bf16(
              ld_frag(wih1 + ((size_t)(1024 + u0 + mf * 16 + lm) << 9) + kk * 32 + lk * 8),
              gb, aIn[mf], 0, 0, 0);
          aHr[mf] = __builtin_amdgcn_mfma_f32_16x16x32_bf16(ld_frag(&smw[f3]), qb, aHr[mf], 0, 0, 0);
          aHz[mf] = __builtin_amdgcn_mfma_f32_16x16x32_bf16(ld_frag(&smw[f3 + 512]), qb, aHz[mf], 0, 0, 0);
          aHn[mf] = __builtin_amdgcn_mfma_f32_16x16x32_bf16(ld_frag(&smw[f3 + 1024]), qb, aHn[mf], 0, 0, 0);
        }
      }
      float v = 0.f;
#pragma unroll
      for (int mf = 0; mf < 2; ++mf) {
        const int ug = u0 + mf * 16 + lk * 4;
        const f32x4 bir = *(const f32x4*)(bih1 + ug);
        const f32x4 biz = *(const f32x4*)(bih1 + 512 + ug);
        const f32x4 bin = *(const f32x4*)(bih1 + 1024 + ug);
        const f32x4 bhr = *(const f32x4*)(bhh1 + ug);
        const f32x4 bhz = *(const f32x4*)(bhh1 + 512 + ug);
        const f32x4 bhn = *(const f32x4*)(bhh1 + 1024 + ug);
        const f32x4 dw4 = *(const f32x4*)(dnnw + ug);
        u32x2 hpu = *(const u32x2*)(S2t + browK + ug);
        float hv[4];
#pragma unroll
        for (int r = 0; r < 4; ++r) {
          float hp = bf2f((unsigned short)((hpu[r >> 1] >> ((r & 1) * 16)) & 0xffff));
          float rr = sigm(aIr[mf][r] + bir[r] + aHr[mf][r] + bhr[r]);
          float zz = sigm(aIz[mf][r] + biz[r] + aHz[mf][r] + bhz[r]);
          float nn = tanh_(aIn[mf][r] + bin[r] + rr * (aHn[mf][r] + bhn[r]));
          hv[r] = nn - nn * zz + zz * hp;
          v += hv[r] * dw4[r];
        }
        st_h4_sys(S2n + browK + ug, hv);
      }
      // dnn head: sum over lk (lanes differing in bits 4..5) -> 32 units
      v += __shfl_xor(v, 16);
      v += __shfl_xor(v, 32);
      if (lk == 0) atomicAdd(&x3[(size_t)brow * 63 + t], v);
      __syncthreads();
      if (tid == 0)
        __hip_atomic_fetch_add(&fL1[(t + 1) * 8 + bt], 1u, __ATOMIC_RELAXED,
                               __HIP_MEMORY_SCOPE_SYSTEM);
    }
  }
}

// ------------------------------- heads -------------------------------------
__global__ __launch_bounds__(64) void head_kernel(
    const float* __restrict__ x3, const float* __restrict__ dnn_b,
    const float* __restrict__ w1, const float* __restrict__ b1,
    const float* __restrict__ w2, const float* __restrict__ b2,
    const float* __restrict__ w3, const float* __restrict__ b3,
    float* __restrict__ out) {
  __shared__ float x3s[63], x4[32], x5[16];
  const int b = blockIdx.x, l = threadIdx.x;
  if (l < 63) x3s[l] = x3[(size_t)b * 63 + l] + dnn_b[0];
  __syncthreads();
  if (l < 32) {
    float s = b1[l];
    for (int t = 0; t < 63; ++t) s += x3s[t] * w1[l * 63 + t];
    x4[l] = s;
  }
  __syncthreads();
  if (l < 16) {
    float s = b2[l];
#pragma unroll
    for (int j = 0; j < 32; ++j) s += x4[j] * w2[l * 32 + j];
    x5[l] = s;
  }
  __syncthreads();
  if (l == 0) {
    float s = b3[0];
#pragma unroll
    for (int j = 0; j < 16; ++j) s += x5[j] * w3[j];
    out[b] = s;
  }
}

// ---------------------------------------------------------------------------
extern "C" void kernel_launch(void* const* d_in, const int* in_sizes, int n_in,
                              void* d_out, int out_size, void* d_ws, size_t ws_size,
                              hipStream_t stream) {
  const float* x    = (const float*)d_in[0];
  const float* wih0 = (const float*)d_in[1];
  const float* whh0 = (const float*)d_in[2];
  const float* bih0 = (const float*)d_in[3];
  const float* bhh0 = (const float*)d_in[4];
  const float* wih1 = (const float*)d_in[5];
  const float* whh1 = (const float*)d_in[6];
  const float* bih1 = (const float*)d_in[7];
  const float* bhh1 = (const float*)d_in[8];
  const float* dnnw = (const float*)d_in[9];
  const float* dnnb = (const float*)d_in[10];
  const float* w1   = (const float*)d_in[11];
  const float* b1   = (const float*)d_in[12];
  const float* w2   = (const float*)d_in[13];
  const float* b2   = (const float*)d_in[14];
  const float* w3   = (const float*)d_in[15];
  const float* b3   = (const float*)d_in[16];
  float* out = (float*)d_out;

  char* p = (char*)d_ws;
  auto alloc = [&](size_t bytes) {
    char* r = p;
    p += (bytes + 255) & ~(size_t)255;
    return r;
  };
  // total ~176 MB
  unsigned short* xbuf = (unsigned short*)alloc((size_t)64512 * 288 * 2);
  unsigned short* S1   = (unsigned short*)alloc((size_t)64 * 1024 * 512 * 2);
  unsigned short* S2   = (unsigned short*)alloc((size_t)64 * 1024 * 512 * 2);
  float* x3            = (float*)alloc((size_t)1024 * 63 * 4);      // 258048 B
  unsigned int* flags  = (unsigned int*)alloc(4096);                // contiguous w/ x3
  unsigned short* wih0b = (unsigned short*)alloc((size_t)1536 * 288 * 2);
  unsigned short* whh0b = (unsigned short*)alloc((size_t)1536 * 512 * 2);
  unsigned short* wih1b = (unsigned short*)alloc((size_t)1536 * 512 * 2);
  unsigned short* whh1b = (unsigned short*)alloc((size_t)1536 * 512 * 2);
  (void)ws_size; (void)in_sizes; (void)n_in; (void)out_size;

  // zero: S1 slot0, S2 slot0, x3+flags (262144 B = 16384 uint4)
  zero_ws_kernel<<<256, 256, 0, stream>>>((uint4*)S1, 65536);
  zero_ws_kernel<<<256, 256, 0, stream>>>((uint4*)S2, 65536);
  zero_ws_kernel<<<64, 256, 0, stream>>>((uint4*)x3, 16384);

  // x -> bf16 padded [64512][288]; weights -> bf16
  convx_kernel<<<18144, 256, 0, stream>>>(x, xbuf);
  conv_pad_kernel<<<216, 256, 0, stream>>>(wih0, wih0b, 1536, 257, 288);
  conv_pad_kernel<<<384, 256, 0, stream>>>(whh0, whh0b, 1536, 512, 512);
  conv_pad_kernel<<<384, 256, 0, stream>>>(wih1, wih1b, 1536, 512, 512);
  conv_pad_kernel<<<384, 256, 0, stream>>>(whh1, whh1b, 1536, 512, 512);

  // allow 160 KB dynamic LDS (weights-in-LDS), then launch persistent kernel
  (void)hipFuncSetAttribute((const void*)gru_persist_kernel,
                            hipFuncAttributeMaxDynamicSharedMemorySize, 163840);
  gru_persist_kernel<<<256, 512, 163840, stream>>>(
      xbuf, wih0b, bih0, whh0b, bhh0, wih1b, whh1b, bih1, bhh1,
      dnnw, x3, S1, S2, flags);

  // heads -> out [1024]
  head_kernel<<<1024, 64, 0, stream>>>(x3, dnnb, w1, b1, w2, b2, w3, b3, out);
}